// Round 11
// baseline (486.507 us; speedup 1.0000x reference)
//
#include <hip/hip_runtime.h>

#define N_ATOMS 100000
#define N_PAIRS 3200000
#define N_PROP 16
#define N_BASIS 10
#define W 16
#define NSUP (N_PAIRS / 32)   // 100000 supers, 32 pairs each
#define SCAN_BLK 1024
#define NB ((N_ATOMS + SCAN_BLK - 1) / SCAN_BLK)   // 98
#define SC 2.88539008177792681f   // 2*log2(e), folded into weights/pre-acts

typedef short  s16x8  __attribute__((ext_vector_type(8)));
typedef float  f32x4  __attribute__((ext_vector_type(4)));
typedef float  f32x16 __attribute__((ext_vector_type(16)));

__device__ __forceinline__ float tanh_pre(float y) {   // y = SC*x
    float e = __builtin_amdgcn_exp2f(y);
    return 1.0f - 2.0f * __builtin_amdgcn_rcpf(e + 1.0f);
}
__device__ __forceinline__ float fast_tanh(float x) {
    float e = __builtin_amdgcn_exp2f(x * SC);
    return 1.0f - 2.0f * __builtin_amdgcn_rcpf(e + 1.0f);
}
__device__ __forceinline__ unsigned short bf16r(float f) {
    union { float f; unsigned u; } v; v.f = f;
    unsigned r = v.u + 0x7FFFu + ((v.u >> 16) & 1u);
    return (unsigned short)(r >> 16);
}
__device__ __forceinline__ unsigned cvt_pk_bf16(float a, float b) {
    unsigned r;
    asm("v_cvt_pk_bf16_f32 %0, %1, %2" : "=v"(r) : "v"(a), "v"(b));
    return r;   // low16 = bf16(a), high16 = bf16(b), RTNE
}
__device__ __forceinline__ float bitf(unsigned u) {
    union { unsigned u; float f; } v; v.u = u; return v.f;
}

// ---------------- pp_pre: fused pi0 per-atom halves (f32, SC+bias folded)
__global__ __launch_bounds__(256) void k_pp_pre(
    const float* __restrict__ p1,
    const float* __restrict__ W0, const float* __restrict__ b0,
    const float* __restrict__ W1, const float* __restrict__ b1,
    const float* __restrict__ Wpi0, const float* __restrict__ bpi0,
    float* __restrict__ ytop, float* __restrict__ ybot)
{
    int a = blockIdx.x * 256 + threadIdx.x;
    if (a >= N_ATOMS) return;
    const float4* src = reinterpret_cast<const float4*>(p1 + (size_t)a * N_PROP);
    float4 v0 = src[0], v1 = src[1], v2 = src[2], v3 = src[3];
    float x[N_PROP] = {v0.x,v0.y,v0.z,v0.w, v1.x,v1.y,v1.z,v1.w,
                       v2.x,v2.y,v2.z,v2.w, v3.x,v3.y,v3.z,v3.w};
    float h[W];
#pragma unroll
    for (int c = 0; c < W; ++c) h[c] = b0[c];
#pragma unroll
    for (int k = 0; k < N_PROP; ++k)
#pragma unroll
        for (int c = 0; c < W; ++c) h[c] += x[k] * W0[k*W + c];
#pragma unroll
    for (int c = 0; c < W; ++c) h[c] = fast_tanh(h[c]);
    float y[W];
#pragma unroll
    for (int c = 0; c < W; ++c) y[c] = b1[c];
#pragma unroll
    for (int k = 0; k < W; ++k)
#pragma unroll
        for (int c = 0; c < W; ++c) y[c] += h[k] * W1[k*W + c];
    float t[W];
#pragma unroll
    for (int c = 0; c < W; ++c) t[c] = fast_tanh(y[c]);

    float yt[W], yb[W];
#pragma unroll
    for (int c = 0; c < W; ++c) { yt[c] = bpi0[c]; yb[c] = 0.0f; }
#pragma unroll
    for (int k = 0; k < W; ++k)
#pragma unroll
        for (int c = 0; c < W; ++c) {
            yt[c] += t[k] * Wpi0[k*W + c];
            yb[c] += t[k] * Wpi0[(W + k)*W + c];
        }
    float4* dt = reinterpret_cast<float4*>(ytop + (size_t)a * W);
    float4* db = reinterpret_cast<float4*>(ybot + (size_t)a * W);
#pragma unroll
    for (int q = 0; q < 4; ++q) {
        dt[q] = make_float4(SC*yt[4*q], SC*yt[4*q+1], SC*yt[4*q+2], SC*yt[4*q+3]);
        db[q] = make_float4(SC*yb[4*q], SC*yb[4*q+1], SC*yb[4*q+2], SC*yb[4*q+3]);
    }
}

// ---------------- pair kernel: 32x32x16 MFMA, one 32-pair super per wave-iter
// Writes ONLY i_pair (contiguous full-line cooperative stores).
__global__ __launch_bounds__(256) void k_pair_mfma(
    const int*   __restrict__ ind2,
    const float* __restrict__ basis,
    const float* __restrict__ ytop,
    const float* __restrict__ ybot,
    const float* __restrict__ Wpi1, const float* __restrict__ bpi1,
    const float* __restrict__ Wii0, const float* __restrict__ Wii1,
    float* __restrict__ i_pair_out)
{
    __shared__ s16x8 aw_lds[5][2][32];   // Wpi1 tiles  [T][h][row]
    __shared__ s16x8 ab_lds[5][2][32];   // bias tiles (rank-1, k==0 column)

    const int lane = threadIdx.x & 63;
    const int wv   = threadIdx.x >> 6;
    const int col  = lane & 31;     // pair slot within super
    const int h    = lane >> 5;     // k-half

    for (int e = threadIdx.x; e < 320; e += 256) {
        int T = e >> 6, hh = (e >> 5) & 1, row = e & 31;
        int colW = (4*(row >> 3) + (row & 3)) * N_BASIS + 2*T + ((row >> 2) & 1);
        s16x8 wfrag, bfrag;
#pragma unroll
        for (int j = 0; j < 8; ++j) {
            int k = 8*hh + j;
            wfrag[j] = (short)bf16r(SC * Wpi1[k*(W*N_BASIS) + colW]);
            bfrag[j] = (short)((k == 0) ? bf16r(SC * bpi1[colW]) : 0);
        }
        aw_lds[T][hh][row] = wfrag;
        ab_lds[T][hh][row] = bfrag;
    }

    s16x8 a3, a4;
#pragma unroll
    for (int j = 0; j < 8; ++j) {
        int k = 8*h + j;
        a3[j] = (short)(col < W ? bf16r(SC * Wii0[k*W + col]) : 0);
        a4[j] = (short)(col < W ? bf16r(SC * Wii1[k*W + col]) : 0);
    }
    s16x8 Bones = {0,0,0,0,0,0,0,0};
    if (h == 0) Bones[0] = (short)0x3F80;   // bf16(1.0) at k==0

    __syncthreads();

    const int stride = gridDim.x * 4;
    int sup = blockIdx.x * 4 + wv;
    if (sup >= NSUP) return;
    const int2* ind2v = reinterpret_cast<const int2*>(ind2);

    // prologue
    int2 ij = ind2v[(size_t)sup * 32 + col];
    f32x4 yt0 = *reinterpret_cast<const f32x4*>(ytop + (size_t)ij.x * W + 8*h);
    f32x4 yt1 = *reinterpret_cast<const f32x4*>(ytop + (size_t)ij.x * W + 8*h + 4);
    f32x4 yb0 = *reinterpret_cast<const f32x4*>(ybot + (size_t)ij.y * W + 8*h);
    f32x4 yb1 = *reinterpret_cast<const f32x4*>(ybot + (size_t)ij.y * W + 8*h + 4);

    for (; sup < NSUP; sup += stride) {
        const int p0 = sup * 32;
        const int p  = p0 + col;
        const int nsup = (sup + stride < NSUP) ? (sup + stride) : sup;

        // (1) issue next ind2 load
        int2 nij = ind2v[(size_t)nsup * 32 + col];

        // (2) pi0: lane's own 8-ch half, no shuffles
        float h0[8];
#pragma unroll
        for (int j = 0; j < 4; ++j) h0[j]     = tanh_pre(yt0[j] + yb0[j]);
#pragma unroll
        for (int j = 0; j < 4; ++j) h0[4 + j] = tanh_pre(yt1[j] + yb1[j]);
        unsigned w0h = cvt_pk_bf16(h0[0], h0[1]);
        unsigned w1h = cvt_pk_bf16(h0[2], h0[3]);
        unsigned w2h = cvt_pk_bf16(h0[4], h0[5]);
        unsigned w3h = cvt_pk_bf16(h0[6], h0[7]);
        unsigned w0l = cvt_pk_bf16(h0[0] - bitf(w0h << 16), h0[1] - bitf(w0h & 0xFFFF0000u));
        unsigned w1l = cvt_pk_bf16(h0[2] - bitf(w1h << 16), h0[3] - bitf(w1h & 0xFFFF0000u));
        unsigned w2l = cvt_pk_bf16(h0[4] - bitf(w2h << 16), h0[5] - bitf(w2h & 0xFFFF0000u));
        unsigned w3l = cvt_pk_bf16(h0[6] - bitf(w3h << 16), h0[7] - bitf(w3h & 0xFFFF0000u));
        union { unsigned u[4]; s16x8 v; } BH, BL;
        BH.u[0] = w0h; BH.u[1] = w1h; BH.u[2] = w2h; BH.u[3] = w3h;
        BL.u[0] = w0l; BL.u[1] = w1l; BL.u[2] = w2l; BL.u[3] = w3l;
        s16x8 B2h = BH.v, B2l = BL.v;

        // (3) basis: 5 float2 loads + half-select
        const float2* bb = reinterpret_cast<const float2*>(basis + (size_t)p * N_BASIS);
        float bsel[5];
#pragma unroll
        for (int q = 0; q < 5; ++q) {
            float2 t2 = bb[q];
            bsel[q] = h ? t2.y : t2.x;   // bas[2q+h]
        }

        // (4) pi1: 5 tiles x (bias + hi + lo) MFMA, static epilogue (ch = reg i)
        float v[16];
#pragma unroll
        for (int i = 0; i < 16; ++i) v[i] = 0.0f;
#pragma unroll
        for (int T = 0; T < 5; ++T) {
            s16x8 af = aw_lds[T][h][col];
            s16x8 ab = ab_lds[T][h][col];
            f32x16 z = {0.0f};
            z = __builtin_amdgcn_mfma_f32_32x32x16_bf16(ab, Bones, z, 0, 0, 0);
            z = __builtin_amdgcn_mfma_f32_32x32x16_bf16(af, B2h,  z, 0, 0, 0);
            z = __builtin_amdgcn_mfma_f32_32x32x16_bf16(af, B2l,  z, 0, 0, 0);
#pragma unroll
            for (int i = 0; i < 16; ++i)
                v[i] += tanh_pre(z[i]) * bsel[T];
        }

        // (5) issue next gathers (nij landed under pi1)
        f32x4 nyt0 = *reinterpret_cast<const f32x4*>(ytop + (size_t)nij.x * W + 8*h);
        f32x4 nyt1 = *reinterpret_cast<const f32x4*>(ytop + (size_t)nij.x * W + 8*h + 4);
        f32x4 nyb0 = *reinterpret_cast<const f32x4*>(ybot + (size_t)nij.y * W + 8*h);
        f32x4 nyb1 = *reinterpret_cast<const f32x4*>(ybot + (size_t)nij.y * W + 8*h + 4);

        // (6) combine bp-halves of v across lane halves (need full v[8h+j])
        float own[8], snd[8];
        if (h == 0) {
#pragma unroll
            for (int j = 0; j < 8; ++j) { own[j] = v[j]; snd[j] = v[8 + j]; }
        } else {
#pragma unroll
            for (int j = 0; j < 8; ++j) { own[j] = v[8 + j]; snd[j] = v[j]; }
        }
        float vf[8];
#pragma unroll
        for (int j = 0; j < 8; ++j) vf[j] = own[j] + __shfl_xor(snd[j], 32);

        // (7) ii0
        union { unsigned u[4]; s16x8 v; } B3u;
        B3u.u[0] = cvt_pk_bf16(vf[0], vf[1]);
        B3u.u[1] = cvt_pk_bf16(vf[2], vf[3]);
        B3u.u[2] = cvt_pk_bf16(vf[4], vf[5]);
        B3u.u[3] = cvt_pk_bf16(vf[6], vf[7]);
        f32x16 ua = {0.0f};
        ua = __builtin_amdgcn_mfma_f32_32x32x16_bf16(a3, B3u.v, ua, 0, 0, 0);
        float u[8];
#pragma unroll
        for (int i = 0; i < 8; ++i) u[i] = tanh_pre(ua[i]);   // rows {0-3,8-11}+4h

        // (8) ii1: swap quads so each lane holds u[8h..8h+7]
        float uo[4], us[4];
        if (h == 0) {
#pragma unroll
            for (int j = 0; j < 4; ++j) { uo[j] = u[j]; us[j] = u[4 + j]; }
        } else {
#pragma unroll
            for (int j = 0; j < 4; ++j) { uo[j] = u[4 + j]; us[j] = u[j]; }
        }
        float ur[4];
#pragma unroll
        for (int j = 0; j < 4; ++j) ur[j] = __shfl_xor(us[j], 32);
        union { unsigned u[4]; s16x8 v; } B4u;
        if (h == 0) {
            B4u.u[0] = cvt_pk_bf16(uo[0], uo[1]);
            B4u.u[1] = cvt_pk_bf16(uo[2], uo[3]);
            B4u.u[2] = cvt_pk_bf16(ur[0], ur[1]);
            B4u.u[3] = cvt_pk_bf16(ur[2], ur[3]);
        } else {
            B4u.u[0] = cvt_pk_bf16(ur[0], ur[1]);
            B4u.u[1] = cvt_pk_bf16(ur[2], ur[3]);
            B4u.u[2] = cvt_pk_bf16(uo[0], uo[1]);
            B4u.u[3] = cvt_pk_bf16(uo[2], uo[3]);
        }
        f32x16 wa = {0.0f};
        wa = __builtin_amdgcn_mfma_f32_32x32x16_bf16(a4, B4u.v, wa, 0, 0, 0);
        float wq[8];
#pragma unroll
        for (int i = 0; i < 8; ++i) wq[i] = tanh_pre(wa[i]);
        // lane (col,h0): wq[0..3]=ch0-3, wq[4..7]=ch8-11; (col,h1): ch4-7, ch12-15

        // (9) full-line cooperative store of 32 consecutive rows (2 KB contiguous)
        const int rk0 = lane & 15;
        const int q   = lane >> 4;
#pragma unroll
        for (int k = 0; k < 2; ++k) {
            int row = 16*k + rk0;
            int src = row + 32*(q & 1);    // q even -> h0 lane, q odd -> h1 lane
            float vA0 = __shfl(wq[0], src), vA1 = __shfl(wq[1], src);
            float vA2 = __shfl(wq[2], src), vA3 = __shfl(wq[3], src);
            float vB0 = __shfl(wq[4], src), vB1 = __shfl(wq[5], src);
            float vB2 = __shfl(wq[6], src), vB3 = __shfl(wq[7], src);
            bool hiq = (q >= 2);
            f32x4 val = { hiq ? vB0 : vA0, hiq ? vB1 : vA1,
                          hiq ? vB2 : vA2, hiq ? vB3 : vA3 };
            __builtin_nontemporal_store(val,
                reinterpret_cast<f32x4*>(i_pair_out + (size_t)(p0 + row) * W + q*4));
        }

        // (10) rotate
        ij = nij;
        yt0 = nyt0; yt1 = nyt1; yb0 = nyb0; yb1 = nyb1;
    }
}

// ---------------- IP pipeline
__global__ __launch_bounds__(256) void k_count(const int* __restrict__ ind2,
                                               unsigned* __restrict__ counts,
                                               unsigned* __restrict__ rank)
{
    int t = blockIdx.x * 256 + threadIdx.x;
    if (t >= N_PAIRS / 2) return;
    int4 ii = reinterpret_cast<const int4*>(ind2)[t];   // pairs 2t (x,y), 2t+1 (z,w)
    unsigned r0 = atomicAdd(&counts[ii.x], 1u);
    unsigned r1 = atomicAdd(&counts[ii.z], 1u);
    uint2 rr; rr.x = r0; rr.y = r1;
    *reinterpret_cast<uint2*>(rank + 2*t) = rr;
}

__global__ __launch_bounds__(SCAN_BLK) void k_scanA(const unsigned* __restrict__ counts,
                                                    unsigned* __restrict__ starts,
                                                    unsigned* __restrict__ bsum)
{
    __shared__ unsigned sc[SCAN_BLK];
    int a = blockIdx.x * SCAN_BLK + threadIdx.x;
    unsigned c = (a < N_ATOMS) ? counts[a] : 0u;
    sc[threadIdx.x] = c;
    __syncthreads();
    for (int off = 1; off < SCAN_BLK; off <<= 1) {
        unsigned v = sc[threadIdx.x];
        unsigned add = (threadIdx.x >= off) ? sc[threadIdx.x - off] : 0u;
        __syncthreads();
        sc[threadIdx.x] = v + add;
        __syncthreads();
    }
    if (a < N_ATOMS) starts[a] = sc[threadIdx.x] - c;
    if (threadIdx.x == SCAN_BLK - 1) bsum[blockIdx.x] = sc[SCAN_BLK - 1];
}

// scanB merged into scanC: each block locally scans the 98 block sums
__global__ __launch_bounds__(SCAN_BLK) void k_scanC(unsigned* __restrict__ starts,
                                                    const unsigned* __restrict__ bsum)
{
    __shared__ unsigned s[128];
    if (threadIdx.x < 128)
        s[threadIdx.x] = (threadIdx.x < NB) ? bsum[threadIdx.x] : 0u;
    __syncthreads();
    for (int off = 1; off < 128; off <<= 1) {
        unsigned x = (threadIdx.x < 128) ? s[threadIdx.x] : 0u;
        unsigned add = (threadIdx.x >= off && threadIdx.x < 128) ? s[threadIdx.x - off] : 0u;
        __syncthreads();
        if (threadIdx.x < 128) s[threadIdx.x] = x + add;
        __syncthreads();
    }
    unsigned boffb = (blockIdx.x == 0) ? 0u : s[blockIdx.x - 1];
    int a = blockIdx.x * SCAN_BLK + threadIdx.x;
    if (a < N_ATOMS) starts[a] += boffb;
}

// fill sorted index: sidx[starts[i] + rank[p]] = p   (4B scatters, ~26MB RFO)
__global__ __launch_bounds__(256) void k_sidx(const int* __restrict__ ind2,
                                              const unsigned* __restrict__ rank,
                                              const unsigned* __restrict__ starts,
                                              unsigned* __restrict__ sidx)
{
    int t = blockIdx.x * 256 + threadIdx.x;
    if (t >= N_PAIRS / 2) return;
    int4 ii = reinterpret_cast<const int4*>(ind2)[t];
    uint2 rr = *reinterpret_cast<const uint2*>(rank + 2*t);
    sidx[starts[ii.x] + rr.x] = (unsigned)(2*t);
    sidx[starts[ii.z] + rr.y] = (unsigned)(2*t + 1);
}

// gather-reduce: 16 rows in flight per wave, rows read 64B from i_pair via sidx
__global__ __launch_bounds__(256) void k_reduce_gather(const unsigned* __restrict__ starts,
                                                       const unsigned* __restrict__ counts,
                                                       const unsigned* __restrict__ sidx,
                                                       const float* __restrict__ i_pair,
                                                       float* __restrict__ p_sum)
{
    int a = blockIdx.x * 4 + (threadIdx.x >> 6);
    if (a >= N_ATOMS) return;
    int lane = threadIdx.x & 63;
    int c4 = lane & 3;          // quarter (ch 4*c4..4*c4+3)
    int q  = lane >> 2;         // row slot 0..15
    unsigned n = counts[a], st = starts[a];
    f32x4 acc = {0.f, 0.f, 0.f, 0.f};
    for (unsigned k = q; k < n; k += 16) {
        unsigned pid = sidx[st + k];
        acc += *reinterpret_cast<const f32x4*>(i_pair + (size_t)pid * W + c4*4);
    }
#pragma unroll
    for (int off = 4; off < 64; off <<= 1) {
        acc[0] += __shfl_xor(acc[0], off);
        acc[1] += __shfl_xor(acc[1], off);
        acc[2] += __shfl_xor(acc[2], off);
        acc[3] += __shfl_xor(acc[3], off);
    }
    if (lane < 4)
        *reinterpret_cast<f32x4*>(p_sum + (size_t)a * W + lane*4) = acc;
}

// ---------------- pp_post
__global__ __launch_bounds__(256) void k_pp_post(
    const float* __restrict__ p_sum,
    const float* __restrict__ W0, const float* __restrict__ W1,
    float* __restrict__ p1_new)
{
    int a = blockIdx.x * 256 + threadIdx.x;
    if (a >= N_ATOMS) return;
    const float4* src = reinterpret_cast<const float4*>(p_sum + (size_t)a * W);
    float4 v0 = src[0], v1 = src[1], v2 = src[2], v3 = src[3];
    float x[W] = {v0.x,v0.y,v0.z,v0.w, v1.x,v1.y,v1.z,v1.w,
                  v2.x,v2.y,v2.z,v2.w, v3.x,v3.y,v3.z,v3.w};
    float h[W];
#pragma unroll
    for (int c = 0; c < W; ++c) h[c] = 0.0f;
#pragma unroll
    for (int k = 0; k < W; ++k)
#pragma unroll
        for (int c = 0; c < W; ++c) h[c] += x[k] * W0[k*W + c];
#pragma unroll
    for (int c = 0; c < W; ++c) h[c] = fast_tanh(h[c]);
    float y[W];
#pragma unroll
    for (int c = 0; c < W; ++c) y[c] = 0.0f;
#pragma unroll
    for (int k = 0; k < W; ++k)
#pragma unroll
        for (int c = 0; c < W; ++c) y[c] += h[k] * W1[k*W + c];
    float4* dst = reinterpret_cast<float4*>(p1_new + (size_t)a * W);
    dst[0] = make_float4(fast_tanh(y[0]),  fast_tanh(y[1]),  fast_tanh(y[2]),  fast_tanh(y[3]));
    dst[1] = make_float4(fast_tanh(y[4]),  fast_tanh(y[5]),  fast_tanh(y[6]),  fast_tanh(y[7]));
    dst[2] = make_float4(fast_tanh(y[8]),  fast_tanh(y[9]),  fast_tanh(y[10]), fast_tanh(y[11]));
    dst[3] = make_float4(fast_tanh(y[12]), fast_tanh(y[13]), fast_tanh(y[14]), fast_tanh(y[15]));
}

extern "C" void kernel_launch(void* const* d_in, const int* in_sizes, int n_in,
                              void* d_out, int out_size, void* d_ws, size_t ws_size,
                              hipStream_t stream) {
    const int*   ind2   = (const int*)d_in[0];
    const float* p1     = (const float*)d_in[1];
    const float* basis  = (const float*)d_in[2];
    const float* Wpre0  = (const float*)d_in[3];
    const float* bpre0  = (const float*)d_in[4];
    const float* Wpre1  = (const float*)d_in[5];
    const float* bpre1  = (const float*)d_in[6];
    const float* Wpi0   = (const float*)d_in[7];
    const float* bpi0   = (const float*)d_in[8];
    const float* Wpi1   = (const float*)d_in[9];
    const float* bpi1   = (const float*)d_in[10];
    const float* Wii0   = (const float*)d_in[11];
    const float* Wii1   = (const float*)d_in[12];
    const float* Wpost0 = (const float*)d_in[13];
    const float* Wpost1 = (const float*)d_in[14];

    float* out    = (float*)d_out;
    float* p1_new = out;                          // (N_ATOMS, W)
    float* i_pair = out + (size_t)N_ATOMS * W;    // (N_PAIRS, W)

    char* ws = (char*)d_ws;
    float*    ytop   = (float*)ws;                                ws += (size_t)N_ATOMS * W * 4;
    float*    ybot   = (float*)ws;                                ws += (size_t)N_ATOMS * W * 4;
    float*    p_sum  = (float*)ws;                                ws += (size_t)N_ATOMS * W * 4;
    unsigned* counts = (unsigned*)ws;                             ws += (size_t)N_ATOMS * 4;
    unsigned* starts = (unsigned*)ws;                             ws += (size_t)N_ATOMS * 4;
    unsigned* bsum   = (unsigned*)ws;                             ws += 1024 * 4;
    unsigned* rank   = (unsigned*)ws;                             ws += (size_t)N_PAIRS * 4;
    unsigned* sidx   = (unsigned*)ws;                             ws += (size_t)N_PAIRS * 4;

    hipMemsetAsync(counts, 0, (size_t)N_ATOMS * sizeof(unsigned), stream);
    k_pp_pre<<<(N_ATOMS + 255) / 256, 256, 0, stream>>>(p1, Wpre0, bpre0, Wpre1, bpre1,
                                                        Wpi0, bpi0, ytop, ybot);
    k_count<<<(N_PAIRS / 2 + 255) / 256, 256, 0, stream>>>(ind2, counts, rank);
    k_scanA<<<NB, SCAN_BLK, 0, stream>>>(counts, starts, bsum);
    k_scanC<<<NB, SCAN_BLK, 0, stream>>>(starts, bsum);
    k_sidx<<<(N_PAIRS / 2 + 255) / 256, 256, 0, stream>>>(ind2, rank, starts, sidx);

    k_pair_mfma<<<2560, 256, 0, stream>>>(ind2, basis, ytop, ybot,
                                          Wpi1, bpi1, Wii0, Wii1, i_pair);
    k_reduce_gather<<<(N_ATOMS + 3) / 4, 256, 0, stream>>>(starts, counts, sidx, i_pair, p_sum);
    k_pp_post<<<(N_ATOMS + 255) / 256, 256, 0, stream>>>(p_sum, Wpost0, Wpost1, p1_new);
}

// Round 12
// 481.870 us; speedup vs baseline: 1.0096x; 1.0096x over previous
//
#include <hip/hip_runtime.h>

#define N_ATOMS 100000
#define N_PAIRS 3200000
#define N_PROP 16
#define N_BASIS 10
#define W 16
#define NSUP (N_PAIRS / 32)   // 100000 supers, 32 pairs each
#define SCAN_BLK 1024
#define NB ((N_ATOMS + SCAN_BLK - 1) / SCAN_BLK)   // 98
#define SC 2.88539008177792681f   // 2*log2(e), folded into weights/pre-acts

typedef short  s16x8  __attribute__((ext_vector_type(8)));
typedef float  f32x4  __attribute__((ext_vector_type(4)));
typedef float  f32x16 __attribute__((ext_vector_type(16)));

__device__ __forceinline__ float tanh_pre(float y) {   // y = SC*x
    float e = __builtin_amdgcn_exp2f(y);
    return 1.0f - 2.0f * __builtin_amdgcn_rcpf(e + 1.0f);
}
__device__ __forceinline__ float fast_tanh(float x) {
    float e = __builtin_amdgcn_exp2f(x * SC);
    return 1.0f - 2.0f * __builtin_amdgcn_rcpf(e + 1.0f);
}
__device__ __forceinline__ unsigned short bf16r(float f) {
    union { float f; unsigned u; } v; v.f = f;
    unsigned r = v.u + 0x7FFFu + ((v.u >> 16) & 1u);
    return (unsigned short)(r >> 16);
}
__device__ __forceinline__ unsigned cvt_pk_bf16(float a, float b) {
    unsigned r;
    asm("v_cvt_pk_bf16_f32 %0, %1, %2" : "=v"(r) : "v"(a), "v"(b));
    return r;   // low16 = bf16(a), high16 = bf16(b), RTNE
}
__device__ __forceinline__ float bitf(unsigned u) {
    union { unsigned u; float f; } v; v.u = u; return v.f;
}

// ---------------- pp_pre: fused pi0 per-atom halves (f32, SC+bias folded)
__global__ __launch_bounds__(256) void k_pp_pre(
    const float* __restrict__ p1,
    const float* __restrict__ W0, const float* __restrict__ b0,
    const float* __restrict__ W1, const float* __restrict__ b1,
    const float* __restrict__ Wpi0, const float* __restrict__ bpi0,
    float* __restrict__ ytop, float* __restrict__ ybot)
{
    int a = blockIdx.x * 256 + threadIdx.x;
    if (a >= N_ATOMS) return;
    const float4* src = reinterpret_cast<const float4*>(p1 + (size_t)a * N_PROP);
    float4 v0 = src[0], v1 = src[1], v2 = src[2], v3 = src[3];
    float x[N_PROP] = {v0.x,v0.y,v0.z,v0.w, v1.x,v1.y,v1.z,v1.w,
                       v2.x,v2.y,v2.z,v2.w, v3.x,v3.y,v3.z,v3.w};
    float h[W];
#pragma unroll
    for (int c = 0; c < W; ++c) h[c] = b0[c];
#pragma unroll
    for (int k = 0; k < N_PROP; ++k)
#pragma unroll
        for (int c = 0; c < W; ++c) h[c] += x[k] * W0[k*W + c];
#pragma unroll
    for (int c = 0; c < W; ++c) h[c] = fast_tanh(h[c]);
    float y[W];
#pragma unroll
    for (int c = 0; c < W; ++c) y[c] = b1[c];
#pragma unroll
    for (int k = 0; k < W; ++k)
#pragma unroll
        for (int c = 0; c < W; ++c) y[c] += h[k] * W1[k*W + c];
    float t[W];
#pragma unroll
    for (int c = 0; c < W; ++c) t[c] = fast_tanh(y[c]);

    float yt[W], yb[W];
#pragma unroll
    for (int c = 0; c < W; ++c) { yt[c] = bpi0[c]; yb[c] = 0.0f; }
#pragma unroll
    for (int k = 0; k < W; ++k)
#pragma unroll
        for (int c = 0; c < W; ++c) {
            yt[c] += t[k] * Wpi0[k*W + c];
            yb[c] += t[k] * Wpi0[(W + k)*W + c];
        }
    float4* dt = reinterpret_cast<float4*>(ytop + (size_t)a * W);
    float4* db = reinterpret_cast<float4*>(ybot + (size_t)a * W);
#pragma unroll
    for (int q = 0; q < 4; ++q) {
        dt[q] = make_float4(SC*yt[4*q], SC*yt[4*q+1], SC*yt[4*q+2], SC*yt[4*q+3]);
        db[q] = make_float4(SC*yb[4*q], SC*yb[4*q+1], SC*yb[4*q+2], SC*yb[4*q+3]);
    }
}

// ---------------- pair kernel: 32x32x16 MFMA, one 32-pair super per wave-iter
// Writes ONLY i_pair, via full-line cooperative stores that stay cache-resident
// (NO nontemporal hint: the reduce gathers these rows right after — L3-warm).
__global__ __launch_bounds__(256) void k_pair_mfma(
    const int*   __restrict__ ind2,
    const float* __restrict__ basis,
    const float* __restrict__ ytop,
    const float* __restrict__ ybot,
    const float* __restrict__ Wpi1, const float* __restrict__ bpi1,
    const float* __restrict__ Wii0, const float* __restrict__ Wii1,
    float* __restrict__ i_pair_out)
{
    __shared__ s16x8 aw_lds[5][2][32];   // Wpi1 tiles  [T][h][row]
    __shared__ s16x8 ab_lds[5][2][32];   // bias tiles (rank-1, k==0 column)

    const int lane = threadIdx.x & 63;
    const int wv   = threadIdx.x >> 6;
    const int col  = lane & 31;     // pair slot within super
    const int h    = lane >> 5;     // k-half

    for (int e = threadIdx.x; e < 320; e += 256) {
        int T = e >> 6, hh = (e >> 5) & 1, row = e & 31;
        int colW = (4*(row >> 3) + (row & 3)) * N_BASIS + 2*T + ((row >> 2) & 1);
        s16x8 wfrag, bfrag;
#pragma unroll
        for (int j = 0; j < 8; ++j) {
            int k = 8*hh + j;
            wfrag[j] = (short)bf16r(SC * Wpi1[k*(W*N_BASIS) + colW]);
            bfrag[j] = (short)((k == 0) ? bf16r(SC * bpi1[colW]) : 0);
        }
        aw_lds[T][hh][row] = wfrag;
        ab_lds[T][hh][row] = bfrag;
    }

    s16x8 a3, a4;
#pragma unroll
    for (int j = 0; j < 8; ++j) {
        int k = 8*h + j;
        a3[j] = (short)(col < W ? bf16r(SC * Wii0[k*W + col]) : 0);
        a4[j] = (short)(col < W ? bf16r(SC * Wii1[k*W + col]) : 0);
    }
    s16x8 Bones = {0,0,0,0,0,0,0,0};
    if (h == 0) Bones[0] = (short)0x3F80;   // bf16(1.0) at k==0

    __syncthreads();

    const int stride = gridDim.x * 4;
    int sup = blockIdx.x * 4 + wv;
    if (sup >= NSUP) return;
    const int2* ind2v = reinterpret_cast<const int2*>(ind2);

    // prologue
    int2 ij = ind2v[(size_t)sup * 32 + col];
    f32x4 yt0 = *reinterpret_cast<const f32x4*>(ytop + (size_t)ij.x * W + 8*h);
    f32x4 yt1 = *reinterpret_cast<const f32x4*>(ytop + (size_t)ij.x * W + 8*h + 4);
    f32x4 yb0 = *reinterpret_cast<const f32x4*>(ybot + (size_t)ij.y * W + 8*h);
    f32x4 yb1 = *reinterpret_cast<const f32x4*>(ybot + (size_t)ij.y * W + 8*h + 4);

    for (; sup < NSUP; sup += stride) {
        const int p0 = sup * 32;
        const int p  = p0 + col;
        const int nsup = (sup + stride < NSUP) ? (sup + stride) : sup;

        // (1) issue next ind2 load
        int2 nij = ind2v[(size_t)nsup * 32 + col];

        // (2) pi0: lane's own 8-ch half, no shuffles
        float h0[8];
#pragma unroll
        for (int j = 0; j < 4; ++j) h0[j]     = tanh_pre(yt0[j] + yb0[j]);
#pragma unroll
        for (int j = 0; j < 4; ++j) h0[4 + j] = tanh_pre(yt1[j] + yb1[j]);
        unsigned w0h = cvt_pk_bf16(h0[0], h0[1]);
        unsigned w1h = cvt_pk_bf16(h0[2], h0[3]);
        unsigned w2h = cvt_pk_bf16(h0[4], h0[5]);
        unsigned w3h = cvt_pk_bf16(h0[6], h0[7]);
        unsigned w0l = cvt_pk_bf16(h0[0] - bitf(w0h << 16), h0[1] - bitf(w0h & 0xFFFF0000u));
        unsigned w1l = cvt_pk_bf16(h0[2] - bitf(w1h << 16), h0[3] - bitf(w1h & 0xFFFF0000u));
        unsigned w2l = cvt_pk_bf16(h0[4] - bitf(w2h << 16), h0[5] - bitf(w2h & 0xFFFF0000u));
        unsigned w3l = cvt_pk_bf16(h0[6] - bitf(w3h << 16), h0[7] - bitf(w3h & 0xFFFF0000u));
        union { unsigned u[4]; s16x8 v; } BH, BL;
        BH.u[0] = w0h; BH.u[1] = w1h; BH.u[2] = w2h; BH.u[3] = w3h;
        BL.u[0] = w0l; BL.u[1] = w1l; BL.u[2] = w2l; BL.u[3] = w3l;
        s16x8 B2h = BH.v, B2l = BL.v;

        // (3) basis: 5 float2 loads + half-select
        const float2* bb = reinterpret_cast<const float2*>(basis + (size_t)p * N_BASIS);
        float bsel[5];
#pragma unroll
        for (int q = 0; q < 5; ++q) {
            float2 t2 = bb[q];
            bsel[q] = h ? t2.y : t2.x;   // bas[2q+h]
        }

        // (4) pi1: 5 tiles x (bias + hi + lo) MFMA, static epilogue (ch = reg i)
        float v[16];
#pragma unroll
        for (int i = 0; i < 16; ++i) v[i] = 0.0f;
#pragma unroll
        for (int T = 0; T < 5; ++T) {
            s16x8 af = aw_lds[T][h][col];
            s16x8 ab = ab_lds[T][h][col];
            f32x16 z = {0.0f};
            z = __builtin_amdgcn_mfma_f32_32x32x16_bf16(ab, Bones, z, 0, 0, 0);
            z = __builtin_amdgcn_mfma_f32_32x32x16_bf16(af, B2h,  z, 0, 0, 0);
            z = __builtin_amdgcn_mfma_f32_32x32x16_bf16(af, B2l,  z, 0, 0, 0);
#pragma unroll
            for (int i = 0; i < 16; ++i)
                v[i] += tanh_pre(z[i]) * bsel[T];
        }

        // (5) issue next gathers (nij landed under pi1)
        f32x4 nyt0 = *reinterpret_cast<const f32x4*>(ytop + (size_t)nij.x * W + 8*h);
        f32x4 nyt1 = *reinterpret_cast<const f32x4*>(ytop + (size_t)nij.x * W + 8*h + 4);
        f32x4 nyb0 = *reinterpret_cast<const f32x4*>(ybot + (size_t)nij.y * W + 8*h);
        f32x4 nyb1 = *reinterpret_cast<const f32x4*>(ybot + (size_t)nij.y * W + 8*h + 4);

        // (6) combine bp-halves of v across lane halves (need full v[8h+j])
        float own[8], snd[8];
        if (h == 0) {
#pragma unroll
            for (int j = 0; j < 8; ++j) { own[j] = v[j]; snd[j] = v[8 + j]; }
        } else {
#pragma unroll
            for (int j = 0; j < 8; ++j) { own[j] = v[8 + j]; snd[j] = v[j]; }
        }
        float vf[8];
#pragma unroll
        for (int j = 0; j < 8; ++j) vf[j] = own[j] + __shfl_xor(snd[j], 32);

        // (7) ii0
        union { unsigned u[4]; s16x8 v; } B3u;
        B3u.u[0] = cvt_pk_bf16(vf[0], vf[1]);
        B3u.u[1] = cvt_pk_bf16(vf[2], vf[3]);
        B3u.u[2] = cvt_pk_bf16(vf[4], vf[5]);
        B3u.u[3] = cvt_pk_bf16(vf[6], vf[7]);
        f32x16 ua = {0.0f};
        ua = __builtin_amdgcn_mfma_f32_32x32x16_bf16(a3, B3u.v, ua, 0, 0, 0);
        float u[8];
#pragma unroll
        for (int i = 0; i < 8; ++i) u[i] = tanh_pre(ua[i]);   // rows {0-3,8-11}+4h

        // (8) ii1: swap quads so each lane holds u[8h..8h+7]
        float uo[4], us[4];
        if (h == 0) {
#pragma unroll
            for (int j = 0; j < 4; ++j) { uo[j] = u[j]; us[j] = u[4 + j]; }
        } else {
#pragma unroll
            for (int j = 0; j < 4; ++j) { uo[j] = u[4 + j]; us[j] = u[j]; }
        }
        float ur[4];
#pragma unroll
        for (int j = 0; j < 4; ++j) ur[j] = __shfl_xor(us[j], 32);
        union { unsigned u[4]; s16x8 v; } B4u;
        if (h == 0) {
            B4u.u[0] = cvt_pk_bf16(uo[0], uo[1]);
            B4u.u[1] = cvt_pk_bf16(uo[2], uo[3]);
            B4u.u[2] = cvt_pk_bf16(ur[0], ur[1]);
            B4u.u[3] = cvt_pk_bf16(ur[2], ur[3]);
        } else {
            B4u.u[0] = cvt_pk_bf16(ur[0], ur[1]);
            B4u.u[1] = cvt_pk_bf16(ur[2], ur[3]);
            B4u.u[2] = cvt_pk_bf16(uo[0], uo[1]);
            B4u.u[3] = cvt_pk_bf16(uo[2], uo[3]);
        }
        f32x16 wa = {0.0f};
        wa = __builtin_amdgcn_mfma_f32_32x32x16_bf16(a4, B4u.v, wa, 0, 0, 0);
        float wq[8];
#pragma unroll
        for (int i = 0; i < 8; ++i) wq[i] = tanh_pre(wa[i]);
        // lane (col,h0): wq[0..3]=ch0-3, wq[4..7]=ch8-11; (col,h1): ch4-7, ch12-15

        // (9) full-line cooperative store of 32 consecutive rows (2 KB contiguous),
        // plain stores -> lines stay in L2/L3 for the reduce gather
        const int rk0 = lane & 15;
        const int q   = lane >> 4;
#pragma unroll
        for (int k = 0; k < 2; ++k) {
            int row = 16*k + rk0;
            int src = row + 32*(q & 1);    // q even -> h0 lane, q odd -> h1 lane
            float vA0 = __shfl(wq[0], src), vA1 = __shfl(wq[1], src);
            float vA2 = __shfl(wq[2], src), vA3 = __shfl(wq[3], src);
            float vB0 = __shfl(wq[4], src), vB1 = __shfl(wq[5], src);
            float vB2 = __shfl(wq[6], src), vB3 = __shfl(wq[7], src);
            bool hiq = (q >= 2);
            f32x4 val = { hiq ? vB0 : vA0, hiq ? vB1 : vA1,
                          hiq ? vB2 : vA2, hiq ? vB3 : vA3 };
            *reinterpret_cast<f32x4*>(i_pair_out + (size_t)(p0 + row) * W + q*4) = val;
        }

        // (10) rotate
        ij = nij;
        yt0 = nyt0; yt1 = nyt1; yb0 = nyb0; yb1 = nyb1;
    }
}

// ---------------- IP pipeline
__global__ __launch_bounds__(256) void k_count(const int* __restrict__ ind2,
                                               unsigned* __restrict__ counts,
                                               unsigned* __restrict__ rank)
{
    int t = blockIdx.x * 256 + threadIdx.x;
    if (t >= N_PAIRS / 2) return;
    int4 ii = reinterpret_cast<const int4*>(ind2)[t];   // pairs 2t (x,y), 2t+1 (z,w)
    unsigned r0 = atomicAdd(&counts[ii.x], 1u);
    unsigned r1 = atomicAdd(&counts[ii.z], 1u);
    uint2 rr; rr.x = r0; rr.y = r1;
    *reinterpret_cast<uint2*>(rank + 2*t) = rr;
}

__global__ __launch_bounds__(SCAN_BLK) void k_scanA(const unsigned* __restrict__ counts,
                                                    unsigned* __restrict__ starts,
                                                    unsigned* __restrict__ bsum)
{
    __shared__ unsigned sc[SCAN_BLK];
    int a = blockIdx.x * SCAN_BLK + threadIdx.x;
    unsigned c = (a < N_ATOMS) ? counts[a] : 0u;
    sc[threadIdx.x] = c;
    __syncthreads();
    for (int off = 1; off < SCAN_BLK; off <<= 1) {
        unsigned v = sc[threadIdx.x];
        unsigned add = (threadIdx.x >= off) ? sc[threadIdx.x - off] : 0u;
        __syncthreads();
        sc[threadIdx.x] = v + add;
        __syncthreads();
    }
    if (a < N_ATOMS) starts[a] = sc[threadIdx.x] - c;
    if (threadIdx.x == SCAN_BLK - 1) bsum[blockIdx.x] = sc[SCAN_BLK - 1];
}

// scanB merged into scanC: each block locally scans the 98 block sums
__global__ __launch_bounds__(SCAN_BLK) void k_scanC(unsigned* __restrict__ starts,
                                                    const unsigned* __restrict__ bsum)
{
    __shared__ unsigned s[128];
    if (threadIdx.x < 128)
        s[threadIdx.x] = (threadIdx.x < NB) ? bsum[threadIdx.x] : 0u;
    __syncthreads();
    for (int off = 1; off < 128; off <<= 1) {
        unsigned x = (threadIdx.x < 128) ? s[threadIdx.x] : 0u;
        unsigned add = (threadIdx.x >= off && threadIdx.x < 128) ? s[threadIdx.x - off] : 0u;
        __syncthreads();
        if (threadIdx.x < 128) s[threadIdx.x] = x + add;
        __syncthreads();
    }
    unsigned boffb = (blockIdx.x == 0) ? 0u : s[blockIdx.x - 1];
    int a = blockIdx.x * SCAN_BLK + threadIdx.x;
    if (a < N_ATOMS) starts[a] += boffb;
}

// fill sorted index: sidx[starts[i] + rank[p]] = p   (4B scatters, ~26MB RFO)
__global__ __launch_bounds__(256) void k_sidx(const int* __restrict__ ind2,
                                              const unsigned* __restrict__ rank,
                                              const unsigned* __restrict__ starts,
                                              unsigned* __restrict__ sidx)
{
    int t = blockIdx.x * 256 + threadIdx.x;
    if (t >= N_PAIRS / 2) return;
    int4 ii = reinterpret_cast<const int4*>(ind2)[t];
    uint2 rr = *reinterpret_cast<const uint2*>(rank + 2*t);
    sidx[starts[ii.x] + rr.x] = (unsigned)(2*t);
    sidx[starts[ii.z] + rr.y] = (unsigned)(2*t + 1);
}

// gather-reduce: 16 rows in flight per wave, rows read 64B from L3-warm i_pair
__global__ __launch_bounds__(256) void k_reduce_gather(const unsigned* __restrict__ starts,
                                                       const unsigned* __restrict__ counts,
                                                       const unsigned* __restrict__ sidx,
                                                       const float* __restrict__ i_pair,
                                                       float* __restrict__ p_sum)
{
    int a = blockIdx.x * 4 + (threadIdx.x >> 6);
    if (a >= N_ATOMS) return;
    int lane = threadIdx.x & 63;
    int c4 = lane & 3;          // quarter (ch 4*c4..4*c4+3)
    int q  = lane >> 2;         // row slot 0..15
    unsigned n = counts[a], st = starts[a];
    f32x4 acc = {0.f, 0.f, 0.f, 0.f};
    for (unsigned k = q; k < n; k += 16) {
        unsigned pid = sidx[st + k];
        acc += *reinterpret_cast<const f32x4*>(i_pair + (size_t)pid * W + c4*4);
    }
#pragma unroll
    for (int off = 4; off < 64; off <<= 1) {
        acc[0] += __shfl_xor(acc[0], off);
        acc[1] += __shfl_xor(acc[1], off);
        acc[2] += __shfl_xor(acc[2], off);
        acc[3] += __shfl_xor(acc[3], off);
    }
    if (lane < 4)
        *reinterpret_cast<f32x4*>(p_sum + (size_t)a * W + lane*4) = acc;
}

// ---------------- pp_post
__global__ __launch_bounds__(256) void k_pp_post(
    const float* __restrict__ p_sum,
    const float* __restrict__ W0, const float* __restrict__ W1,
    float* __restrict__ p1_new)
{
    int a = blockIdx.x * 256 + threadIdx.x;
    if (a >= N_ATOMS) return;
    const float4* src = reinterpret_cast<const float4*>(p_sum + (size_t)a * W);
    float4 v0 = src[0], v1 = src[1], v2 = src[2], v3 = src[3];
    float x[W] = {v0.x,v0.y,v0.z,v0.w, v1.x,v1.y,v1.z,v1.w,
                  v2.x,v2.y,v2.z,v2.w, v3.x,v3.y,v3.z,v3.w};
    float h[W];
#pragma unroll
    for (int c = 0; c < W; ++c) h[c] = 0.0f;
#pragma unroll
    for (int k = 0; k < W; ++k)
#pragma unroll
        for (int c = 0; c < W; ++c) h[c] += x[k] * W0[k*W + c];
#pragma unroll
    for (int c = 0; c < W; ++c) h[c] = fast_tanh(h[c]);
    float y[W];
#pragma unroll
    for (int c = 0; c < W; ++c) y[c] = 0.0f;
#pragma unroll
    for (int k = 0; k < W; ++k)
#pragma unroll
        for (int c = 0; c < W; ++c) y[c] += h[k] * W1[k*W + c];
    float4* dst = reinterpret_cast<float4*>(p1_new + (size_t)a * W);
    dst[0] = make_float4(fast_tanh(y[0]),  fast_tanh(y[1]),  fast_tanh(y[2]),  fast_tanh(y[3]));
    dst[1] = make_float4(fast_tanh(y[4]),  fast_tanh(y[5]),  fast_tanh(y[6]),  fast_tanh(y[7]));
    dst[2] = make_float4(fast_tanh(y[8]),  fast_tanh(y[9]),  fast_tanh(y[10]), fast_tanh(y[11]));
    dst[3] = make_float4(fast_tanh(y[12]), fast_tanh(y[13]), fast_tanh(y[14]), fast_tanh(y[15]));
}

extern "C" void kernel_launch(void* const* d_in, const int* in_sizes, int n_in,
                              void* d_out, int out_size, void* d_ws, size_t ws_size,
                              hipStream_t stream) {
    const int*   ind2   = (const int*)d_in[0];
    const float* p1     = (const float*)d_in[1];
    const float* basis  = (const float*)d_in[2];
    const float* Wpre0  = (const float*)d_in[3];
    const float* bpre0  = (const float*)d_in[4];
    const float* Wpre1  = (const float*)d_in[5];
    const float* bpre1  = (const float*)d_in[6];
    const float* Wpi0   = (const float*)d_in[7];
    const float* bpi0   = (const float*)d_in[8];
    const float* Wpi1   = (const float*)d_in[9];
    const float* bpi1   = (const float*)d_in[10];
    const float* Wii0   = (const float*)d_in[11];
    const float* Wii1   = (const float*)d_in[12];
    const float* Wpost0 = (const float*)d_in[13];
    const float* Wpost1 = (const float*)d_in[14];

    float* out    = (float*)d_out;
    float* p1_new = out;                          // (N_ATOMS, W)
    float* i_pair = out + (size_t)N_ATOMS * W;    // (N_PAIRS, W)

    char* ws = (char*)d_ws;
    float*    ytop   = (float*)ws;                                ws += (size_t)N_ATOMS * W * 4;
    float*    ybot   = (float*)ws;                                ws += (size_t)N_ATOMS * W * 4;
    float*    p_sum  = (float*)ws;                                ws += (size_t)N_ATOMS * W * 4;
    unsigned* counts = (unsigned*)ws;                             ws += (size_t)N_ATOMS * 4;
    unsigned* starts = (unsigned*)ws;                             ws += (size_t)N_ATOMS * 4;
    unsigned* bsum   = (unsigned*)ws;                             ws += 1024 * 4;
    unsigned* rank   = (unsigned*)ws;                             ws += (size_t)N_PAIRS * 4;
    unsigned* sidx   = (unsigned*)ws;                             ws += (size_t)N_PAIRS * 4;

    hipMemsetAsync(counts, 0, (size_t)N_ATOMS * sizeof(unsigned), stream);
    k_pp_pre<<<(N_ATOMS + 255) / 256, 256, 0, stream>>>(p1, Wpre0, bpre0, Wpre1, bpre1,
                                                        Wpi0, bpi0, ytop, ybot);
    k_count<<<(N_PAIRS / 2 + 255) / 256, 256, 0, stream>>>(ind2, counts, rank);
    k_scanA<<<NB, SCAN_BLK, 0, stream>>>(counts, starts, bsum);
    k_scanC<<<NB, SCAN_BLK, 0, stream>>>(starts, bsum);
    k_sidx<<<(N_PAIRS / 2 + 255) / 256, 256, 0, stream>>>(ind2, rank, starts, sidx);

    k_pair_mfma<<<2560, 256, 0, stream>>>(ind2, basis, ytop, ybot,
                                          Wpi1, bpi1, Wii0, Wii1, i_pair);
    k_reduce_gather<<<(N_ATOMS + 3) / 4, 256, 0, stream>>>(starts, counts, sidx, i_pair, p_sum);
    k_pp_post<<<(N_ATOMS + 255) / 256, 256, 0, stream>>>(p_sum, Wpost0, Wpost1, p1_new);
}